// Round 5
// baseline (2438.326 us; speedup 1.0000x reference)
//
#include <hip/hip_runtime.h>
#include <cstdint>
#include <cstddef>

// SAGE-LSTM R5: split each LSTM layer into
//  (A) k_xgemm: Xg[n,t,:] = gather(x)@W_ih^T + bsum  -- non-recurrent streaming
//      GEMM. W_ih in VGPRs (read once per block), gathers double-buffered via
//      LDS. Output written in MFMA C-fragment order (bf16).
//  (B) k_lstm_rec: gates = Xg(t) + h(t-1)@W_hh^T; W_hh fragments in LDS
//      (128KB, loaded once per block -> no per-step weight refetch, the R4
//      killer), Xg prefetched one step ahead into registers.
// R4 evidence: FETCH 1.73GB/dispatch = weight slab evicted every t-step by the
// gather stream (5MB/step/XCD > 4MB L2); MfmaUtil 12%, latency-bound.

constexpr int IN  = 128;
constexpr int DEG = 16;

typedef short bf16x8 __attribute__((ext_vector_type(8)));
typedef float f32x16 __attribute__((ext_vector_type(16)));
typedef unsigned int u32x4 __attribute__((ext_vector_type(4)));

__device__ __forceinline__ float fsigmoid(float x) {
    float e = __expf(-x);
    return __builtin_amdgcn_rcpf(1.0f + e);
}
__device__ __forceinline__ float ftanh(float x) {
    float e = __expf(-2.0f * x);
    return __fmaf_rn(2.0f, __builtin_amdgcn_rcpf(1.0f + e), -1.0f);
}
__device__ __forceinline__ uint32_t pack2bf16(float a, float b) {
    uint32_t ua = __float_as_uint(a) + 0x8000u;
    uint32_t ub = __float_as_uint(b) + 0x8000u;
    return (ua >> 16) | (ub & 0xFFFF0000u);
}

// ---------- prep kernels ----------

__global__ void k_transpose(const float* __restrict__ src, float* __restrict__ dst,
                            int R, int C) {
    int i = blockIdx.x * blockDim.x + threadIdx.x;
    if (i < R * C) { int r = i / C, c = i - r * C; dst[c * R + r] = src[i]; }
}

__global__ void k_bias_sum(const float* __restrict__ a, const float* __restrict__ b,
                           float* __restrict__ o, int n) {
    int i = blockIdx.x * blockDim.x + threadIdx.x;
    if (i < n) o[i] = a[i] + b[i];
}

__global__ void k_cast_bf16(const float* __restrict__ src, ushort* __restrict__ dst, int n) {
    int i = (blockIdx.x * blockDim.x + threadIdx.x) * 4;
    if (i + 3 < n) {
        float4 v = *(const float4*)(src + i);
        uint2 d; d.x = pack2bf16(v.x, v.y); d.y = pack2bf16(v.z, v.w);
        *(uint2*)(dst + i) = d;
    } else {
        for (int k = i; k < n; ++k)
            dst[k] = (ushort)((__float_as_uint(src[k]) + 0x8000u) >> 16);
    }
}

// Pack one [512 x 128] weight (row-major) into MFMA B-fragment order, K=128:
// frag[tid] for tid = (kst*16 + tile)*64 + lane; B[k][n]: n = tile*32+(lane&31),
// k = kst*16 + (lane>>5)*8 + j. tile = g*4 + w (col = g*128 + w*32).
__global__ void k_pack_w8(const float* __restrict__ wsrc, u32x4* __restrict__ frag) {
    int tid  = blockIdx.x * 256 + threadIdx.x;   // 0..8191
    int lane = tid & 63;
    int tile = (tid >> 6) & 15;
    int kst  = tid >> 10;                        // 0..7
    int n     = tile * 32 + (lane & 31);
    int kbase = kst * 16 + (lane >> 5) * 8;
    float v[8];
#pragma unroll
    for (int j = 0; j < 8; ++j) v[j] = wsrc[n * 128 + kbase + j];
    u32x4 d;
    d.x = pack2bf16(v[0], v[1]);
    d.y = pack2bf16(v[2], v[3]);
    d.z = pack2bf16(v[4], v[5]);
    d.w = pack2bf16(v[6], v[7]);
    frag[tid] = d;
}

// ---------- kernel A: Xg = gather(x) @ W_ih^T + bsum ----------
// Block = 64 nodes x 16 steps = 1024 M-rows = 32 M-tiles, processed in 8
// chunks of 4 M-tiles, gather staged double-buffered in LDS. W_ih fragments
// in VGPRs (8 kst x 4 g x 16B = 128 VGPR/lane), loaded once.
__global__ __launch_bounds__(256, 2) void k_xgemm(
    const ushort* __restrict__ x,       // [N,128] bf16 gather source
    const int*    __restrict__ nbr,     // [N,16]
    const u32x4*  __restrict__ wih,     // 8192 B-frags
    const float*  __restrict__ bsum,    // [512]
    u32x4*        __restrict__ xg,      // out: frags, 2KB each
    int node_base, int N)
{
    __shared__ u32x4 a_buf[2][4][16][33];   // [buf][mt][kgrp][row(+pad)] ~66KB
    __shared__ int   idxs[DEG * 64];        // [t][m]

    const int tid   = threadIdx.x;
    const int lane  = tid & 63;
    const int w     = tid >> 6;
    const int mrow  = lane & 31;
    const int khalf = lane >> 5;
    const int node0 = node_base + blockIdx.x * 64;

    for (int i = tid; i < 64 * DEG; i += 256) {
        int m = i >> 4, t = i & 15;
        int gn = node0 + m; if (gn >= N) gn = N - 1;
        idxs[t * 64 + m] = nbr[gn * DEG + t];
    }

    u32x4 wreg[8][4];
#pragma unroll
    for (int kst = 0; kst < 8; ++kst)
#pragma unroll
        for (int g = 0; g < 4; ++g)
            wreg[kst][g] = wih[(kst * 16 + g * 4 + w) * 64 + lane];

    float binit[4];
#pragma unroll
    for (int g = 0; g < 4; ++g) binit[g] = bsum[g * 128 + w * 32 + (lane & 31)];

    __syncthreads();

    // stage chunk c (4 M-tiles = 128 rows) into buffer c&1
    auto stage = [&](int c) {
        int b = c & 1;
#pragma unroll
        for (int p = 0; p < 2; ++p) {
            int rl  = (tid >> 2) + p * 64;       // 0..127
            int t   = c * 2 + (rl >> 6);
            int m   = rl & 63;
            int mt  = (rl >> 5) & 3;
            int row = rl & 31;
            const u32x4* src = (const u32x4*)(x + (size_t)idxs[t * 64 + m] * IN);
#pragma unroll
            for (int q = 0; q < 4; ++q) {
                int kg = q * 4 + (tid & 3);
                a_buf[b][mt][kg][row] = __builtin_nontemporal_load(src + kg);
            }
        }
    };

    stage(0);
    __syncthreads();

    for (int c = 0; c < 8; ++c) {
        if (c < 7) stage(c + 1);
        int b = c & 1;
#pragma unroll
        for (int mt = 0; mt < 4; ++mt) {
            f32x16 acc[4];
#pragma unroll
            for (int g = 0; g < 4; ++g)
#pragma unroll
                for (int r = 0; r < 16; ++r) acc[g][r] = binit[g];
#pragma unroll
            for (int kst = 0; kst < 8; ++kst) {
                bf16x8 a = __builtin_bit_cast(bf16x8, a_buf[b][mt][kst * 2 + khalf][mrow]);
#pragma unroll
                for (int g = 0; g < 4; ++g)
                    acc[g] = __builtin_amdgcn_mfma_f32_32x32x16_bf16(
                        a, __builtin_bit_cast(bf16x8, wreg[kst][g]), acc[g], 0, 0, 0);
            }
            int mtg = blockIdx.x * 32 + c * 4 + mt;
#pragma unroll
            for (int g = 0; g < 4; ++g) {
                u32x4 d0, d1;
                d0.x = pack2bf16(acc[g][0],  acc[g][1]);
                d0.y = pack2bf16(acc[g][2],  acc[g][3]);
                d0.z = pack2bf16(acc[g][4],  acc[g][5]);
                d0.w = pack2bf16(acc[g][6],  acc[g][7]);
                d1.x = pack2bf16(acc[g][8],  acc[g][9]);
                d1.y = pack2bf16(acc[g][10], acc[g][11]);
                d1.z = pack2bf16(acc[g][12], acc[g][13]);
                d1.w = pack2bf16(acc[g][14], acc[g][15]);
                u32x4* dst = xg + ((size_t)mtg * 16 + g * 4 + w) * 128 + lane * 2;
                dst[0] = d0;
                dst[1] = d1;
            }
        }
        __syncthreads();
    }
}

// ---------- kernel B: recurrent LSTM over precomputed Xg ----------
// Block = 64 nodes, 4 waves. W_hh frags in LDS (128KB, loaded once). Per step:
// acc init from Xg regs (prefetched 1 step ahead), 8 kst x 8 MFMA from LDS,
// cell update, h round-trip through padded h_frag.
__global__ __launch_bounds__(256, 1) void k_lstm_rec(
    const u32x4* __restrict__ xg,       // frags from k_xgemm
    const u32x4* __restrict__ whh,      // 8192 B-frags
    ushort*      __restrict__ h_out,    // [N,128] bf16
    int node_base, int N)
{
    __shared__ u32x4 whh_lds[8192];     // 128KB
    __shared__ u32x4 h_frag[16 * 65];   // 16.25KB, padded

    const int tid   = threadIdx.x;
    const int lane  = tid & 63;
    const int w     = tid >> 6;
    const int mrow  = lane & 31;
    const int khalf = lane >> 5;
    const int node0 = node_base + blockIdx.x * 64;

    for (int i = tid; i < 8192; i += 256) whh_lds[i] = whh[i];
    for (int i = tid; i < 16 * 65; i += 256) h_frag[i] = u32x4{0u, 0u, 0u, 0u};

    float cst[2][16];
#pragma unroll
    for (int Mt = 0; Mt < 2; ++Mt)
#pragma unroll
        for (int r = 0; r < 16; ++r) cst[Mt][r] = 0.0f;

    const u32x4* xbase = xg + (size_t)blockIdx.x * 32 * 16 * 128;
    // frag offset for (t,Mt,g): ((t*2+Mt)*16 + g*4 + w)*128 + lane*2 (+0/1)

    u32x4 xqA[16], xqB[16];   // [ (Mt*4+g)*2 + half ]
#pragma unroll
    for (int Mt = 0; Mt < 2; ++Mt)
#pragma unroll
        for (int g = 0; g < 4; ++g) {
            const u32x4* p = xbase + ((size_t)(0 * 2 + Mt) * 16 + g * 4 + w) * 128 + lane * 2;
            xqA[(Mt * 4 + g) * 2]     = p[0];
            xqA[(Mt * 4 + g) * 2 + 1] = p[1];
        }

    __syncthreads();   // whh_lds + h_frag zeros ready

    auto step = [&](int t, u32x4* cur, u32x4* nxt) {
        // acc init from cur (Xg already includes bias)
        f32x16 acc[2][4];
#pragma unroll
        for (int Mt = 0; Mt < 2; ++Mt)
#pragma unroll
            for (int g = 0; g < 4; ++g)
#pragma unroll
                for (int k = 0; k < 8; ++k) {
                    uint32_t v = cur[(Mt * 4 + g) * 2 + (k >> 2)][k & 3];
                    acc[Mt][g][2 * k]     = __uint_as_float(v << 16);
                    acc[Mt][g][2 * k + 1] = __uint_as_float(v & 0xFFFF0000u);
                }

        __syncthreads();   // h_frag(t-1) writes visible

#pragma unroll
        for (int kst = 0; kst < 8; ++kst) {
            bf16x8 a0 = __builtin_bit_cast(bf16x8, h_frag[(kst * 2 + khalf) * 65 + mrow]);
            bf16x8 a1 = __builtin_bit_cast(bf16x8, h_frag[(kst * 2 + khalf) * 65 + 32 + mrow]);
#pragma unroll
            for (int g = 0; g < 4; ++g) {
                bf16x8 b = __builtin_bit_cast(bf16x8, whh_lds[(kst * 16 + g * 4 + w) * 64 + lane]);
                acc[0][g] = __builtin_amdgcn_mfma_f32_32x32x16_bf16(a0, b, acc[0][g], 0, 0, 0);
                acc[1][g] = __builtin_amdgcn_mfma_f32_32x32x16_bf16(a1, b, acc[1][g], 0, 0, 0);
            }
        }

        __syncthreads();   // all reads of h_frag(t-1) done

        // prefetch next step's Xg (consumed ~1 update later -> latency hidden)
        if (t < 15) {
#pragma unroll
            for (int Mt = 0; Mt < 2; ++Mt)
#pragma unroll
                for (int g = 0; g < 4; ++g) {
                    const u32x4* p = xbase + ((size_t)((t + 1) * 2 + Mt) * 16 + g * 4 + w) * 128 + lane * 2;
                    nxt[(Mt * 4 + g) * 2]     = p[0];
                    nxt[(Mt * 4 + g) * 2 + 1] = p[1];
                }
        }

        // cell update + h write (A-frag layout, padded stride 65)
#pragma unroll
        for (int Mt = 0; Mt < 2; ++Mt) {
#pragma unroll
            for (int r = 0; r < 16; ++r) {
                float iv = fsigmoid(acc[Mt][0][r]);
                float fv = fsigmoid(acc[Mt][1][r]);
                float gv = ftanh(acc[Mt][2][r]);
                float ov = fsigmoid(acc[Mt][3][r]);
                float cv = __fmaf_rn(fv, cst[Mt][r], iv * gv);
                cst[Mt][r] = cv;
                float hv = ov * ftanh(cv);
                uint32_t hb = __float_as_uint(hv) + 0x8000u;
                uint32_t pb = (uint32_t)__shfl_xor((int)hb, 1, 64);
                if ((lane & 1) == 0) {
                    int row = Mt * 32 + (r & 3) + 8 * (r >> 2) + 4 * khalf;
                    int j   = w * 32 + (lane & 31);
                    ((uint32_t*)h_frag)[((j >> 3) * 65 + row) * 4 + ((lane >> 1) & 3)] =
                        (hb >> 16) | (pb & 0xFFFF0000u);
                }
            }
        }
    };

#pragma unroll 1
    for (int tt = 0; tt < 8; ++tt) {
        step(2 * tt,     xqA, xqB);
        step(2 * tt + 1, xqB, xqA);
    }

    __syncthreads();
    for (int i = tid; i < 64 * IN; i += 256) {
        int m = i >> 7, j = i & 127;
        int gn = node0 + m;
        if (gn < N)
            h_out[(size_t)gn * IN + j] =
                ((const ushort*)h_frag)[((j >> 3) * 65 + m) * 8 + (j & 7)];
    }
}

// ---------- output linear (fp32 math, bf16 inputs) ----------

template <int NOUT, int ACT, typename OutT>
__global__ __launch_bounds__(256) void k_out_linear(
    const ushort* __restrict__ x, const ushort* __restrict__ h,
    const float* __restrict__ wTs, const float* __restrict__ wTn,
    const float* __restrict__ bias, OutT* __restrict__ out, int N)
{
    constexpr int NPS = 32 / (256 / NOUT);
    __shared__ alignas(16) float x_lds[32][IN];
    __shared__ alignas(16) float h_lds[32][IN];

    const int tid  = threadIdx.x;
    const int j    = tid % NOUT;
    const int slot = tid / NOUT;
    const int node0 = blockIdx.x * 32;

    for (int i = tid; i < 32 * (IN / 8); i += 256) {
        int n = i >> 4, u4 = i & 15;
        int gn = node0 + n; if (gn >= N) gn = N - 1;
        u32x4 xv = *(const u32x4*)(x + (size_t)gn * IN + u4 * 8);
        u32x4 hv = *(const u32x4*)(h + (size_t)gn * IN + u4 * 8);
        float* xd = &x_lds[n][u4 * 8];
        float* hd = &h_lds[n][u4 * 8];
        xd[0] = __uint_as_float(xv.x << 16); xd[1] = __uint_as_float(xv.x & 0xFFFF0000u);
        xd[2] = __uint_as_float(xv.y << 16); xd[3] = __uint_as_float(xv.y & 0xFFFF0000u);
        xd[4] = __uint_as_float(xv.z << 16); xd[5] = __uint_as_float(xv.z & 0xFFFF0000u);
        xd[6] = __uint_as_float(xv.w << 16); xd[7] = __uint_as_float(xv.w & 0xFFFF0000u);
        hd[0] = __uint_as_float(hv.x << 16); hd[1] = __uint_as_float(hv.x & 0xFFFF0000u);
        hd[2] = __uint_as_float(hv.y << 16); hd[3] = __uint_as_float(hv.y & 0xFFFF0000u);
        hd[4] = __uint_as_float(hv.z << 16); hd[5] = __uint_as_float(hv.z & 0xFFFF0000u);
        hd[6] = __uint_as_float(hv.w << 16); hd[7] = __uint_as_float(hv.w & 0xFFFF0000u);
    }
    __syncthreads();

    float acc[NPS];
    const float bj = bias[j];
#pragma unroll
    for (int n = 0; n < NPS; ++n) acc[n] = bj;

#pragma unroll 2
    for (int k = 0; k < IN; ++k) {
        const float ws = wTs[k * NOUT + j];
        const float wn = wTn[k * NOUT + j];
#pragma unroll
        for (int n = 0; n < NPS; ++n) {
            acc[n] = __fmaf_rn(x_lds[slot * NPS + n][k], ws,
                     __fmaf_rn(h_lds[slot * NPS + n][k], wn, acc[n]));
        }
    }

#pragma unroll
    for (int n = 0; n < NPS; ++n) {
        int gn = node0 + slot * NPS + n;
        if (gn < N) {
            float v = acc[n];
            v = (ACT == 0) ? fmaxf(v, 0.0f) : fsigmoid(v);
            if constexpr (sizeof(OutT) == 2)
                out[(size_t)gn * NOUT + j] = (OutT)((__float_as_uint(v) + 0x8000u) >> 16);
            else
                out[(size_t)gn * NOUT + j] = v;
        }
    }
}

extern "C" void kernel_launch(void* const* d_in, const int* in_sizes, int n_in,
                              void* d_out, int out_size, void* d_ws, size_t ws_size,
                              hipStream_t stream)
{
    const float* feats    = (const float*)d_in[0];
    const int*   nbr      = (const int*)  d_in[1];
    const float* w_ih1    = (const float*)d_in[2];
    const float* w_hh1    = (const float*)d_in[3];
    const float* b_ih1    = (const float*)d_in[4];
    const float* b_hh1    = (const float*)d_in[5];
    const float* w_self1  = (const float*)d_in[6];
    const float* w_neigh1 = (const float*)d_in[7];
    const float* b1       = (const float*)d_in[8];
    const float* w_ih2    = (const float*)d_in[9];
    const float* w_hh2    = (const float*)d_in[10];
    const float* b_ih2    = (const float*)d_in[11];
    const float* b_hh2    = (const float*)d_in[12];
    const float* w_self2  = (const float*)d_in[13];
    const float* w_neigh2 = (const float*)d_in[14];
    const float* b2       = (const float*)d_in[15];
    float* out = (float*)d_out;

    const int N = in_sizes[0] / IN;   // 50000

    char* ws = (char*)d_ws;
    size_t off = 0;
    auto alloc = [&](size_t bytes) -> void* {
        void* p = (void*)(ws + off);
        off += (bytes + 255) & ~(size_t)255;
        return p;
    };
    u32x4*  wfrag_ih1 = (u32x4*)alloc(8192 * 16);
    u32x4*  wfrag_hh1 = (u32x4*)alloc(8192 * 16);
    u32x4*  wfrag_ih2 = (u32x4*)alloc(8192 * 16);
    u32x4*  wfrag_hh2 = (u32x4*)alloc(8192 * 16);
    float*  wT_self1  = (float*)alloc(128 * 128 * 4);
    float*  wT_neigh1 = (float*)alloc(128 * 128 * 4);
    float*  wT_self2  = (float*)alloc(64 * 128 * 4);
    float*  wT_neigh2 = (float*)alloc(64 * 128 * 4);
    float*  bsum1     = (float*)alloc(512 * 4);
    float*  bsum2     = (float*)alloc(512 * 4);
    ushort* feats_bf  = (ushort*)alloc((size_t)N * 128 * 2);
    ushort* h_buf     = (ushort*)alloc((size_t)N * 128 * 2);
    ushort* out1      = (ushort*)alloc((size_t)N * 128 * 2);

    // Xg chunk buffer: 16KB per node (16 t x 512 cols x 2B). Chunk to fit ws.
    size_t avail = (ws_size > off + 256) ? (ws_size - off - 256) : 0;
    long long chunk = (long long)(avail / 16384) & ~63LL;
    long long Nceil = (N + 63) & ~63LL;
    if (chunk > Nceil) chunk = Nceil;
    if (chunk < 64) chunk = 64;       // ws assumed to cover at least one block
    u32x4* xg_buf = (u32x4*)alloc((size_t)chunk * 16384);

    // prep
    k_pack_w8<<<dim3(32), dim3(256), 0, stream>>>(w_ih1, wfrag_ih1);
    k_pack_w8<<<dim3(32), dim3(256), 0, stream>>>(w_hh1, wfrag_hh1);
    k_pack_w8<<<dim3(32), dim3(256), 0, stream>>>(w_ih2, wfrag_ih2);
    k_pack_w8<<<dim3(32), dim3(256), 0, stream>>>(w_hh2, wfrag_hh2);
    k_transpose<<<dim3((128 * 128 + 255) / 256), dim3(256), 0, stream>>>(w_self1, wT_self1, 128, 128);
    k_transpose<<<dim3((128 * 128 + 255) / 256), dim3(256), 0, stream>>>(w_neigh1, wT_neigh1, 128, 128);
    k_transpose<<<dim3((64 * 128 + 255) / 256), dim3(256), 0, stream>>>(w_self2, wT_self2, 64, 128);
    k_transpose<<<dim3((64 * 128 + 255) / 256), dim3(256), 0, stream>>>(w_neigh2, wT_neigh2, 64, 128);
    k_bias_sum<<<dim3(2), dim3(256), 0, stream>>>(b_ih1, b_hh1, bsum1, 512);
    k_bias_sum<<<dim3(2), dim3(256), 0, stream>>>(b_ih2, b_hh2, bsum2, 512);
    k_cast_bf16<<<dim3((N * 128 / 4 + 255) / 256), dim3(256), 0, stream>>>(feats, feats_bf, N * 128);

    const int nblk32 = (N + 31) / 32;

    // layer 1 (chunked over nodes to fit Xg in ws)
    for (long long base = 0; base < N; base += chunk) {
        int cnt = (int)((N - base < chunk) ? (N - base) : chunk);
        int nb  = (cnt + 63) / 64;
        k_xgemm<<<dim3(nb), dim3(256), 0, stream>>>(feats_bf, nbr, wfrag_ih1, bsum1, xg_buf, (int)base, N);
        k_lstm_rec<<<dim3(nb), dim3(256), 0, stream>>>(xg_buf, wfrag_hh1, h_buf, (int)base, N);
    }
    k_out_linear<128, 0, ushort><<<dim3(nblk32), dim3(256), 0, stream>>>(feats_bf, h_buf, wT_self1, wT_neigh1, b1, out1, N);

    // layer 2
    for (long long base = 0; base < N; base += chunk) {
        int cnt = (int)((N - base < chunk) ? (N - base) : chunk);
        int nb  = (cnt + 63) / 64;
        k_xgemm<<<dim3(nb), dim3(256), 0, stream>>>(out1, nbr, wfrag_ih2, bsum2, xg_buf, (int)base, N);
        k_lstm_rec<<<dim3(nb), dim3(256), 0, stream>>>(xg_buf, wfrag_hh2, h_buf, (int)base, N);
    }
    k_out_linear<64, 1, float><<<dim3(nblk32), dim3(256), 0, stream>>>(out1, h_buf, wT_self2, wT_neigh2, b2, out, N);
}

// Round 6
// 897.806 us; speedup vs baseline: 2.7159x; 2.7159x over previous
//
#include <hip/hip_runtime.h>
#include <cstdint>
#include <cstddef>

// SAGE-LSTM R6: gather commutes with the x-GEMM (Xg[n,t]=Xu[nbr[n,t]] where
// Xu = x@W_ih^T + bsum over UNIQUE nodes). So:
//  (A) k_xu: dense MFMA GEMM over N unique rows -> Xu (51MB, L3-resident),
//      stored swizzled so the recurrent gather is one 8B load per (row,lane)
//      directly into C-fragment positions.
//  (B) k_lstm_rec2: block=64 nodes, 512 thr (8 waves: w=wv&3 gate-col group,
//      mt=wv>>2 node half). W_hh frags in LDS (128KB, loaded once -> zero
//      per-step weight traffic, the R4 killer). Per step: acc init from Xu
//      prefetch regs, 8kst x 4 MFMA per wave, cell update, h round-trip in
//      padded LDS. Xu prefetch issued after MFMA barrier so the compiler's
//      vmcnt-drain at the next barrier is ~1000cyc downstream.
// R5 evidence: Xg materialization = 819MB write + 819MB read per layer
// (xgemm 2.6TB/s store-bound, 465us/layer) -> removed entirely.

constexpr int IN  = 128;
constexpr int DEG = 16;

typedef short bf16x8 __attribute__((ext_vector_type(8)));
typedef float f32x16 __attribute__((ext_vector_type(16)));
typedef unsigned int u32x4 __attribute__((ext_vector_type(4)));
typedef unsigned int u32x2 __attribute__((ext_vector_type(2)));

__device__ __forceinline__ float fsigmoid(float x) {
    float e = __expf(-x);
    return __builtin_amdgcn_rcpf(1.0f + e);
}
__device__ __forceinline__ float ftanh(float x) {
    float e = __expf(-2.0f * x);
    return __fmaf_rn(2.0f, __builtin_amdgcn_rcpf(1.0f + e), -1.0f);
}
__device__ __forceinline__ uint32_t pack2bf16(float a, float b) {
    uint32_t ua = __float_as_uint(a) + 0x8000u;
    uint32_t ub = __float_as_uint(b) + 0x8000u;
    return (ua >> 16) | (ub & 0xFFFF0000u);
}

// ---------- prep kernels ----------

__global__ void k_transpose(const float* __restrict__ src, float* __restrict__ dst,
                            int R, int C) {
    int i = blockIdx.x * blockDim.x + threadIdx.x;
    if (i < R * C) { int r = i / C, c = i - r * C; dst[c * R + r] = src[i]; }
}

__global__ void k_bias_sum(const float* __restrict__ a, const float* __restrict__ b,
                           float* __restrict__ o, int n) {
    int i = blockIdx.x * blockDim.x + threadIdx.x;
    if (i < n) o[i] = a[i] + b[i];
}

__global__ void k_cast_bf16(const float* __restrict__ src, ushort* __restrict__ dst, int n) {
    int i = (blockIdx.x * blockDim.x + threadIdx.x) * 4;
    if (i + 3 < n) {
        float4 v = *(const float4*)(src + i);
        uint2 d; d.x = pack2bf16(v.x, v.y); d.y = pack2bf16(v.z, v.w);
        *(uint2*)(dst + i) = d;
    } else {
        for (int k = i; k < n; ++k)
            dst[k] = (ushort)((__float_as_uint(src[k]) + 0x8000u) >> 16);
    }
}

// Pack one [512 x 128] weight (row-major) into MFMA B-fragment order, K=128:
// frag[(kst*16 + tile)*64 + lane]; B[k][n]: n = tile*32+(lane&31),
// k = kst*16 + (lane>>5)*8 + j. tile = g*4 + w (gate col = g*128 + w*32).
__global__ void k_pack_w8(const float* __restrict__ wsrc, u32x4* __restrict__ frag) {
    int tid  = blockIdx.x * 256 + threadIdx.x;   // 0..8191
    int lane = tid & 63;
    int tile = (tid >> 6) & 15;
    int kst  = tid >> 10;                        // 0..7
    int n     = tile * 32 + (lane & 31);
    int kbase = kst * 16 + (lane >> 5) * 8;
    float v[8];
#pragma unroll
    for (int j = 0; j < 8; ++j) v[j] = wsrc[n * 128 + kbase + j];
    u32x4 d;
    d.x = pack2bf16(v[0], v[1]);
    d.y = pack2bf16(v[2], v[3]);
    d.z = pack2bf16(v[4], v[5]);
    d.w = pack2bf16(v[6], v[7]);
    frag[tid] = d;
}

// ---------- kernel A: Xu = x @ W_ih^T + bsum, swizzled store ----------
// Block = 64 rows, 256 threads. W_ih frags in VGPRs (128/lane). Output row
// layout: u16 at [(w*32+mrow)*4 + g] -> each (Mt,r) is one 8B store; the
// recurrent gather reads one u32x2 per (row,lane).
__global__ __launch_bounds__(256, 2) void k_xu(
    const ushort* __restrict__ x,       // [N,128] bf16
    const u32x4*  __restrict__ wih,     // 8192 B-frags
    const float*  __restrict__ bsum,    // [512]
    u32x2*        __restrict__ xu,      // [Nceil][128] u32x2 (swizzled rows)
    int N)
{
    __shared__ u32x4 a_buf[16][66];     // [kgrp][row 0..63 + pad]

    const int tid   = threadIdx.x;
    const int lane  = tid & 63;
    const int w     = tid >> 6;
    const int mrow  = lane & 31;
    const int khalf = lane >> 5;
    const int node0 = blockIdx.x * 64;

    u32x4 wreg[8][4];
#pragma unroll
    for (int kst = 0; kst < 8; ++kst)
#pragma unroll
        for (int g = 0; g < 4; ++g)
            wreg[kst][g] = wih[(kst * 16 + g * 4 + w) * 64 + lane];

    float binit[4];
#pragma unroll
    for (int g = 0; g < 4; ++g) binit[g] = bsum[g * 128 + w * 32 + mrow];

    // stage 64 rows (bf16 row order == A-frag k-order): 4 lanes/row
    {
        int m_st = tid >> 2, c4 = tid & 3;
        int gn = node0 + m_st; if (gn >= N) gn = N - 1;
        const u32x4* src = (const u32x4*)(x + (size_t)gn * IN);
#pragma unroll
        for (int q = 0; q < 4; ++q) {
            int kg = q * 4 + c4;
            a_buf[kg][m_st] = src[kg];
        }
    }
    __syncthreads();

    f32x16 acc[2][4];
#pragma unroll
    for (int Mt = 0; Mt < 2; ++Mt)
#pragma unroll
        for (int g = 0; g < 4; ++g)
#pragma unroll
            for (int r = 0; r < 16; ++r) acc[Mt][g][r] = binit[g];

#pragma unroll
    for (int kst = 0; kst < 8; ++kst) {
        bf16x8 a0 = __builtin_bit_cast(bf16x8, a_buf[kst * 2 + khalf][mrow]);
        bf16x8 a1 = __builtin_bit_cast(bf16x8, a_buf[kst * 2 + khalf][32 + mrow]);
#pragma unroll
        for (int g = 0; g < 4; ++g) {
            acc[0][g] = __builtin_amdgcn_mfma_f32_32x32x16_bf16(
                a0, __builtin_bit_cast(bf16x8, wreg[kst][g]), acc[0][g], 0, 0, 0);
            acc[1][g] = __builtin_amdgcn_mfma_f32_32x32x16_bf16(
                a1, __builtin_bit_cast(bf16x8, wreg[kst][g]), acc[1][g], 0, 0, 0);
        }
    }

    const int coff = w * 32 + mrow;   // u32x2 offset within row
#pragma unroll
    for (int Mt = 0; Mt < 2; ++Mt)
#pragma unroll
        for (int r = 0; r < 16; ++r) {
            int m = Mt * 32 + (r & 3) + 8 * (r >> 2) + 4 * khalf;
            u32x2 d;
            d.x = pack2bf16(acc[Mt][0][r], acc[Mt][1][r]);
            d.y = pack2bf16(acc[Mt][2][r], acc[Mt][3][r]);
            xu[(size_t)(node0 + m) * 128 + coff] = d;
        }
}

// ---------- kernel B: recurrent LSTM, gathered-Xu + h@W_hh^T ----------
__global__ __launch_bounds__(512, 1) void k_lstm_rec2(
    const u32x2* __restrict__ xu,       // swizzled Xu rows
    const int*   __restrict__ nbr,      // [N,16]
    const u32x4* __restrict__ whh,      // 8192 B-frags
    ushort*      __restrict__ h_out,    // [N,128] bf16
    int N)
{
    __shared__ u32x4 whh_lds[8192];     // 128KB
    __shared__ u32x4 h_frag[16 * 65];   // 16.25KB, padded stride
    __shared__ int   idxs[DEG * 64];    // [t][m]

    const int tid   = threadIdx.x;
    const int lane  = tid & 63;
    const int wv    = tid >> 6;         // wave 0..7
    const int w     = wv & 3;           // gate-col group
    const int mt    = wv >> 2;          // node half (0..1)
    const int mrow  = lane & 31;
    const int khalf = lane >> 5;
    const int node0 = blockIdx.x * 64;

    for (int i = tid; i < 8192; i += 512) whh_lds[i] = whh[i];
    for (int i = tid; i < 16 * 65; i += 512) h_frag[i] = u32x4{0u, 0u, 0u, 0u};
    for (int i = tid; i < 64 * DEG; i += 512) {
        int m = i >> 4, t = i & 15;
        int gn = node0 + m; if (gn >= N) gn = N - 1;
        idxs[t * 64 + m] = nbr[gn * DEG + t];
    }

    // my 16 node rows (fixed across steps): m_r = mt*32 + (r&3)+8*(r>>2)+4*khalf
    int mloc[16];
#pragma unroll
    for (int r = 0; r < 16; ++r)
        mloc[r] = mt * 32 + (r & 3) + 8 * (r >> 2) + 4 * khalf;

    const int coff = w * 32 + mrow;

    float cst[16];
#pragma unroll
    for (int r = 0; r < 16; ++r) cst[r] = 0.0f;

    u32x2 xpA[16], xpB[16];

    auto prefetch = [&](int t, u32x2* dst) {
#pragma unroll
        for (int r = 0; r < 16; ++r) {
            int idx = idxs[t * 64 + mloc[r]];
            dst[r] = xu[(size_t)idx * 128 + coff];
        }
    };

    __syncthreads();          // idxs ready (whh/h barrier folded in below)
    prefetch(0, xpA);
    __syncthreads();          // whh_lds + h zeros + xp issued

    auto step = [&](int t, u32x2* cur, u32x2* nxt) {
        // acc init from gathered Xu (includes bias)
        f32x16 acc[4];
#pragma unroll
        for (int r = 0; r < 16; ++r) {
            u32x2 v = cur[r];
            acc[0][r] = __uint_as_float(v.x << 16);
            acc[1][r] = __uint_as_float(v.x & 0xFFFF0000u);
            acc[2][r] = __uint_as_float(v.y << 16);
            acc[3][r] = __uint_as_float(v.y & 0xFFFF0000u);
        }

        __syncthreads();      // h(t-1) writes visible

#pragma unroll
        for (int kst = 0; kst < 8; ++kst) {
            bf16x8 a = __builtin_bit_cast(bf16x8,
                h_frag[(kst * 2 + khalf) * 65 + mt * 32 + mrow]);
#pragma unroll
            for (int g = 0; g < 4; ++g) {
                bf16x8 b = __builtin_bit_cast(bf16x8,
                    whh_lds[(kst * 16 + g * 4 + w) * 64 + lane]);
                acc[g] = __builtin_amdgcn_mfma_f32_32x32x16_bf16(a, b, acc[g], 0, 0, 0);
            }
        }

        __syncthreads();      // h(t-1) reads done

        // prefetch next step's Xu now: next barrier (and its vmcnt drain) is
        // a full cell-update + acc-init away
        if (t < 15) prefetch(t + 1, nxt);

        // cell update + h(t) write (A-frag layout, padded stride 65)
#pragma unroll
        for (int r = 0; r < 16; ++r) {
            float iv = fsigmoid(acc[0][r]);
            float fv = fsigmoid(acc[1][r]);
            float gv = ftanh(acc[2][r]);
            float ov = fsigmoid(acc[3][r]);
            float cv = __fmaf_rn(fv, cst[r], iv * gv);
            cst[r] = cv;
            float hv = ov * ftanh(cv);
            uint32_t hb = __float_as_uint(hv) + 0x8000u;
            uint32_t pb = (uint32_t)__shfl_xor((int)hb, 1, 64);
            if ((lane & 1) == 0) {
                int row = mloc[r];
                int j   = w * 32 + mrow;
                ((uint32_t*)h_frag)[((j >> 3) * 65 + row) * 4 + ((lane >> 1) & 3)] =
                    (hb >> 16) | (pb & 0xFFFF0000u);
            }
        }
    };

#pragma unroll 1
    for (int tt = 0; tt < 8; ++tt) {
        step(2 * tt,     xpA, xpB);
        step(2 * tt + 1, xpB, xpA);
    }

    __syncthreads();
    for (int i = tid; i < 64 * IN; i += 512) {
        int m = i >> 7, j = i & 127;
        int gn = node0 + m;
        if (gn < N)
            h_out[(size_t)gn * IN + j] =
                ((const ushort*)h_frag)[((j >> 3) * 65 + m) * 8 + (j & 7)];
    }
}

// ---------- output linear (fp32 math, bf16 inputs) ----------

template <int NOUT, int ACT, typename OutT>
__global__ __launch_bounds__(256) void k_out_linear(
    const ushort* __restrict__ x, const ushort* __restrict__ h,
    const float* __restrict__ wTs, const float* __restrict__ wTn,
    const float* __restrict__ bias, OutT* __restrict__ out, int N)
{
    constexpr int NPS = 32 / (256 / NOUT);
    __shared__ alignas(16) float x_lds[32][IN];
    __shared__ alignas(16) float h_lds[32][IN];

    const int tid  = threadIdx.x;
    const int j    = tid % NOUT;
    const int slot = tid / NOUT;
    const int node0 = blockIdx.x * 32;

    for (int i = tid; i < 32 * (IN / 8); i += 256) {
        int n = i >> 4, u4 = i & 15;
        int gn = node0 + n; if (gn >= N) gn = N - 1;
        u32x4 xv = *(const u32x4*)(x + (size_t)gn * IN + u4 * 8);
        u32x4 hv = *(const u32x4*)(h + (size_t)gn * IN + u4 * 8);
        float* xd = &x_lds[n][u4 * 8];
        float* hd = &h_lds[n][u4 * 8];
        xd[0] = __uint_as_float(xv.x << 16); xd[1] = __uint_as_float(xv.x & 0xFFFF0000u);
        xd[2] = __uint_as_float(xv.y << 16); xd[3] = __uint_as_float(xv.y & 0xFFFF0000u);
        xd[4] = __uint_as_float(xv.z << 16); xd[5] = __uint_as_float(xv.z & 0xFFFF0000u);
        xd[6] = __uint_as_float(xv.w << 16); xd[7] = __uint_as_float(xv.w & 0xFFFF0000u);
        hd[0] = __uint_as_float(hv.x << 16); hd[1] = __uint_as_float(hv.x & 0xFFFF0000u);
        hd[2] = __uint_as_float(hv.y << 16); hd[3] = __uint_as_float(hv.y & 0xFFFF0000u);
        hd[4] = __uint_as_float(hv.z << 16); hd[5] = __uint_as_float(hv.z & 0xFFFF0000u);
        hd[6] = __uint_as_float(hv.w << 16); hd[7] = __uint_as_float(hv.w & 0xFFFF0000u);
    }
    __syncthreads();

    float acc[NPS];
    const float bj = bias[j];
#pragma unroll
    for (int n = 0; n < NPS; ++n) acc[n] = bj;

#pragma unroll 2
    for (int k = 0; k < IN; ++k) {
        const float ws = wTs[k * NOUT + j];
        const float wn = wTn[k * NOUT + j];
#pragma unroll
        for (int n = 0; n < NPS; ++n) {
            acc[n] = __fmaf_rn(x_lds[slot * NPS + n][k], ws,
                     __fmaf_rn(h_lds[slot * NPS + n][k], wn, acc[n]));
        }
    }

#pragma unroll
    for (int n = 0; n < NPS; ++n) {
        int gn = node0 + slot * NPS + n;
        if (gn < N) {
            float v = acc[n];
            v = (ACT == 0) ? fmaxf(v, 0.0f) : fsigmoid(v);
            if constexpr (sizeof(OutT) == 2)
                out[(size_t)gn * NOUT + j] = (OutT)((__float_as_uint(v) + 0x8000u) >> 16);
            else
                out[(size_t)gn * NOUT + j] = v;
        }
    }
}

extern "C" void kernel_launch(void* const* d_in, const int* in_sizes, int n_in,
                              void* d_out, int out_size, void* d_ws, size_t ws_size,
                              hipStream_t stream)
{
    const float* feats    = (const float*)d_in[0];
    const int*   nbr      = (const int*)  d_in[1];
    const float* w_ih1    = (const float*)d_in[2];
    const float* w_hh1    = (const float*)d_in[3];
    const float* b_ih1    = (const float*)d_in[4];
    const float* b_hh1    = (const float*)d_in[5];
    const float* w_self1  = (const float*)d_in[6];
    const float* w_neigh1 = (const float*)d_in[7];
    const float* b1       = (const float*)d_in[8];
    const float* w_ih2    = (const float*)d_in[9];
    const float* w_hh2    = (const float*)d_in[10];
    const float* b_ih2    = (const float*)d_in[11];
    const float* b_hh2    = (const float*)d_in[12];
    const float* w_self2  = (const float*)d_in[13];
    const float* w_neigh2 = (const float*)d_in[14];
    const float* b2       = (const float*)d_in[15];
    float* out = (float*)d_out;

    const int N = in_sizes[0] / IN;   // 50000
    const long long Nceil = (N + 63) & ~63LL;

    char* ws = (char*)d_ws;
    size_t off = 0;
    auto alloc = [&](size_t bytes) -> void* {
        void* p = (void*)(ws + off);
        off += (bytes + 255) & ~(size_t)255;
        return p;
    };
    u32x4*  wfrag_ih1 = (u32x4*)alloc(8192 * 16);
    u32x4*  wfrag_hh1 = (u32x4*)alloc(8192 * 16);
    u32x4*  wfrag_ih2 = (u32x4*)alloc(8192 * 16);
    u32x4*  wfrag_hh2 = (u32x4*)alloc(8192 * 16);
    float*  wT_self1  = (float*)alloc(128 * 128 * 4);
    float*  wT_neigh1 = (float*)alloc(128 * 128 * 4);
    float*  wT_self2  = (float*)alloc(64 * 128 * 4);
    float*  wT_neigh2 = (float*)alloc(64 * 128 * 4);
    float*  bsum1     = (float*)alloc(512 * 4);
    float*  bsum2     = (float*)alloc(512 * 4);
    ushort* feats_bf  = (ushort*)alloc((size_t)N * 128 * 2);
    ushort* h_buf     = (ushort*)alloc((size_t)N * 128 * 2);
    ushort* out1      = (ushort*)alloc((size_t)N * 128 * 2);
    u32x2*  xu_buf    = (u32x2*)alloc((size_t)Nceil * 128 * 8);   // 51.25MB

    // prep
    k_pack_w8<<<dim3(32), dim3(256), 0, stream>>>(w_ih1, wfrag_ih1);
    k_pack_w8<<<dim3(32), dim3(256), 0, stream>>>(w_hh1, wfrag_hh1);
    k_pack_w8<<<dim3(32), dim3(256), 0, stream>>>(w_ih2, wfrag_ih2);
    k_pack_w8<<<dim3(32), dim3(256), 0, stream>>>(w_hh2, wfrag_hh2);
    k_transpose<<<dim3((128 * 128 + 255) / 256), dim3(256), 0, stream>>>(w_self1, wT_self1, 128, 128);
    k_transpose<<<dim3((128 * 128 + 255) / 256), dim3(256), 0, stream>>>(w_neigh1, wT_neigh1, 128, 128);
    k_transpose<<<dim3((64 * 128 + 255) / 256), dim3(256), 0, stream>>>(w_self2, wT_self2, 64, 128);
    k_transpose<<<dim3((64 * 128 + 255) / 256), dim3(256), 0, stream>>>(w_neigh2, wT_neigh2, 64, 128);
    k_bias_sum<<<dim3(2), dim3(256), 0, stream>>>(b_ih1, b_hh1, bsum1, 512);
    k_bias_sum<<<dim3(2), dim3(256), 0, stream>>>(b_ih2, b_hh2, bsum2, 512);
    k_cast_bf16<<<dim3((N * 128 / 4 + 255) / 256), dim3(256), 0, stream>>>(feats, feats_bf, N * 128);

    const int nblk64 = (int)(Nceil / 64);
    const int nblk32 = (N + 31) / 32;

    // layer 1
    k_xu<<<dim3(nblk64), dim3(256), 0, stream>>>(feats_bf, wfrag_ih1, bsum1, xu_buf, N);
    k_lstm_rec2<<<dim3(nblk64), dim3(512), 0, stream>>>(xu_buf, nbr, wfrag_hh1, h_buf, N);
    k_out_linear<128, 0, ushort><<<dim3(nblk32), dim3(256), 0, stream>>>(feats_bf, h_buf, wT_self1, wT_neigh1, b1, out1, N);

    // layer 2
    k_xu<<<dim3(nblk64), dim3(256), 0, stream>>>(out1, wfrag_ih2, bsum2, xu_buf, N);
    k_lstm_rec2<<<dim3(nblk64), dim3(512), 0, stream>>>(xu_buf, nbr, wfrag_hh2, h_buf, N);
    k_out_linear<64, 1, float><<<dim3(nblk32), dim3(256), 0, stream>>>(out1, h_buf, wT_self2, wT_neigh2, b2, out, N);
}

// Round 7
// 797.820 us; speedup vs baseline: 3.0562x; 1.1253x over previous
//
#include <hip/hip_runtime.h>
#include <cstdint>
#include <cstddef>

// SAGE-LSTM R7: k_lstm_rec3 restructure.
//  - Xu gather staged into LDS via global_load_lds width=16 (1 wave-instr per
//    1KB row), double-buffered; issue after barrier-A so the vmcnt(0) drain at
//    barrier-B gives a full MFMA+cell of latency cover. (R6: 16x8B register
//    loads, cover = cell-update only -> 1.16TB/s latency-bound gather.)
//  - W_hh B-frags in 128 VGPRs/wave (wave = its gate group) -> kills the
//    320KB/block-step LDS B-read traffic of R6.
//  - Block = 32 nodes / 4 waves / 74.3KB LDS -> 2 blocks/CU, cross-block
//    overlap at barriers. __launch_bounds__(256,2) caps regs at 256.

constexpr int IN  = 128;
constexpr int DEG = 16;

typedef short bf16x8 __attribute__((ext_vector_type(8)));
typedef float f32x16 __attribute__((ext_vector_type(16)));
typedef unsigned int u32x4 __attribute__((ext_vector_type(4)));
typedef unsigned int u32x2 __attribute__((ext_vector_type(2)));

__device__ __forceinline__ float fsigmoid(float x) {
    float e = __expf(-x);
    return __builtin_amdgcn_rcpf(1.0f + e);
}
__device__ __forceinline__ float ftanh(float x) {
    float e = __expf(-2.0f * x);
    return __fmaf_rn(2.0f, __builtin_amdgcn_rcpf(1.0f + e), -1.0f);
}
__device__ __forceinline__ uint32_t pack2bf16(float a, float b) {
    uint32_t ua = __float_as_uint(a) + 0x8000u;
    uint32_t ub = __float_as_uint(b) + 0x8000u;
    return (ua >> 16) | (ub & 0xFFFF0000u);
}

// async global->LDS, 16B per lane; lds base wave-uniform, data lands at
// lds + lane*16. gsrc is per-lane.
__device__ __forceinline__ void gld_lds16(const void* gsrc, void* ldst) {
    __builtin_amdgcn_global_load_lds(
        (const __attribute__((address_space(1))) unsigned int*)gsrc,
        (__attribute__((address_space(3))) unsigned int*)ldst,
        16, 0, 0);
}

// ---------- prep kernels ----------

__global__ void k_transpose(const float* __restrict__ src, float* __restrict__ dst,
                            int R, int C) {
    int i = blockIdx.x * blockDim.x + threadIdx.x;
    if (i < R * C) { int r = i / C, c = i - r * C; dst[c * R + r] = src[i]; }
}

__global__ void k_bias_sum(const float* __restrict__ a, const float* __restrict__ b,
                           float* __restrict__ o, int n) {
    int i = blockIdx.x * blockDim.x + threadIdx.x;
    if (i < n) o[i] = a[i] + b[i];
}

__global__ void k_cast_bf16(const float* __restrict__ src, ushort* __restrict__ dst, int n) {
    int i = (blockIdx.x * blockDim.x + threadIdx.x) * 4;
    if (i + 3 < n) {
        float4 v = *(const float4*)(src + i);
        uint2 d; d.x = pack2bf16(v.x, v.y); d.y = pack2bf16(v.z, v.w);
        *(uint2*)(dst + i) = d;
    } else {
        for (int k = i; k < n; ++k)
            dst[k] = (ushort)((__float_as_uint(src[k]) + 0x8000u) >> 16);
    }
}

// Pack one [512 x 128] weight (row-major) into MFMA B-fragment order, K=128:
// frag[(kst*16 + tile)*64 + lane]; B[k][n]: n = tile*32+(lane&31),
// k = kst*16 + (lane>>5)*8 + j. tile = g*4 + w (gate col = g*128 + w*32).
__global__ void k_pack_w8(const float* __restrict__ wsrc, u32x4* __restrict__ frag) {
    int tid  = blockIdx.x * 256 + threadIdx.x;   // 0..8191
    int lane = tid & 63;
    int tile = (tid >> 6) & 15;
    int kst  = tid >> 10;                        // 0..7
    int n     = tile * 32 + (lane & 31);
    int kbase = kst * 16 + (lane >> 5) * 8;
    float v[8];
#pragma unroll
    for (int j = 0; j < 8; ++j) v[j] = wsrc[n * 128 + kbase + j];
    u32x4 d;
    d.x = pack2bf16(v[0], v[1]);
    d.y = pack2bf16(v[2], v[3]);
    d.z = pack2bf16(v[4], v[5]);
    d.w = pack2bf16(v[6], v[7]);
    frag[tid] = d;
}

// ---------- kernel A: Xu = x @ W_ih^T + bsum, swizzled row store ----------
__global__ __launch_bounds__(256, 2) void k_xu(
    const ushort* __restrict__ x,       // [N,128] bf16
    const u32x4*  __restrict__ wih,     // 8192 B-frags
    const float*  __restrict__ bsum,    // [512]
    u32x2*        __restrict__ xu,      // [Nceil][128] u32x2 (1KB rows)
    int N)
{
    __shared__ u32x4 a_buf[16][66];

    const int tid   = threadIdx.x;
    const int lane  = tid & 63;
    const int w     = tid >> 6;
    const int mrow  = lane & 31;
    const int khalf = lane >> 5;
    const int node0 = blockIdx.x * 64;

    u32x4 wreg[8][4];
#pragma unroll
    for (int kst = 0; kst < 8; ++kst)
#pragma unroll
        for (int g = 0; g < 4; ++g)
            wreg[kst][g] = wih[(kst * 16 + g * 4 + w) * 64 + lane];

    float binit[4];
#pragma unroll
    for (int g = 0; g < 4; ++g) binit[g] = bsum[g * 128 + w * 32 + mrow];

    {
        int m_st = tid >> 2, c4 = tid & 3;
        int gn = node0 + m_st; if (gn >= N) gn = N - 1;
        const u32x4* src = (const u32x4*)(x + (size_t)gn * IN);
#pragma unroll
        for (int q = 0; q < 4; ++q) {
            int kg = q * 4 + c4;
            a_buf[kg][m_st] = src[kg];
        }
    }
    __syncthreads();

    f32x16 acc[2][4];
#pragma unroll
    for (int Mt = 0; Mt < 2; ++Mt)
#pragma unroll
        for (int g = 0; g < 4; ++g)
#pragma unroll
            for (int r = 0; r < 16; ++r) acc[Mt][g][r] = binit[g];

#pragma unroll
    for (int kst = 0; kst < 8; ++kst) {
        bf16x8 a0 = __builtin_bit_cast(bf16x8, a_buf[kst * 2 + khalf][mrow]);
        bf16x8 a1 = __builtin_bit_cast(bf16x8, a_buf[kst * 2 + khalf][32 + mrow]);
#pragma unroll
        for (int g = 0; g < 4; ++g) {
            acc[0][g] = __builtin_amdgcn_mfma_f32_32x32x16_bf16(
                a0, __builtin_bit_cast(bf16x8, wreg[kst][g]), acc[0][g], 0, 0, 0);
            acc[1][g] = __builtin_amdgcn_mfma_f32_32x32x16_bf16(
                a1, __builtin_bit_cast(bf16x8, wreg[kst][g]), acc[1][g], 0, 0, 0);
        }
    }

    const int coff = w * 32 + mrow;
#pragma unroll
    for (int Mt = 0; Mt < 2; ++Mt)
#pragma unroll
        for (int r = 0; r < 16; ++r) {
            int m = Mt * 32 + (r & 3) + 8 * (r >> 2) + 4 * khalf;
            u32x2 d;
            d.x = pack2bf16(acc[Mt][0][r], acc[Mt][1][r]);
            d.y = pack2bf16(acc[Mt][2][r], acc[Mt][3][r]);
            xu[(size_t)(node0 + m) * 128 + coff] = d;
        }
}

// ---------- kernel B: recurrent LSTM ----------
// Block = 32 nodes, 4 waves (wave = gate group). W_hh in VGPRs. Per step:
// acc init from staged Xu rows (LDS), 8 kst MFMA (A from h_frag, B regs),
// cell update, h write. Stage(t+1) issued after barrier-A -> vmcnt drain at
// barrier-B = full-step latency cover.
__global__ __launch_bounds__(256, 2) void k_lstm_rec3(
    const u32x2* __restrict__ xu,       // 1KB swizzled rows
    const int*   __restrict__ nbr,      // [N,16]
    const u32x4* __restrict__ whh,      // 8192 B-frags
    ushort*      __restrict__ h_out,    // [N,128] bf16
    int N)
{
    __shared__ u32x4 stage[2][32][64];   // 64KB: [buf][row][16B chunk]
    __shared__ u32x4 h_frag[16 * 33];    // 8.25KB padded
    __shared__ int   idxs[DEG * 32];     // 2KB [t][m]

    const int tid   = threadIdx.x;
    const int lane  = tid & 63;
    const int w     = tid >> 6;          // wave = gate group 0..3
    const int mrow  = lane & 31;
    const int khalf = lane >> 5;
    const int node0 = blockIdx.x * 32;
    const int coff  = w * 32 + mrow;

    for (int i = tid; i < 32 * DEG; i += 256) {
        int m = i & 31, t = i >> 5;
        int gn = node0 + m; if (gn >= N) gn = N - 1;
        idxs[t * 32 + m] = nbr[gn * DEG + t];
    }
    for (int i = tid; i < 16 * 33; i += 256) h_frag[i] = u32x4{0u, 0u, 0u, 0u};
    __syncthreads();                     // idxs ready for staging

    // prime stage(0): wave w stages rows w*8..w*8+7
#pragma unroll
    for (int r8 = 0; r8 < 8; ++r8) {
        int m = w * 8 + r8;
        int idx = idxs[0 * 32 + m];
        const char* row = (const char*)xu + (size_t)idx * 1024;
        gld_lds16(row + lane * 16, &stage[0][m][0]);
    }

    // W_hh fragments for my gate group (128 VGPRs); overlaps stage latency
    u32x4 wreg[8][4];
#pragma unroll
    for (int kst = 0; kst < 8; ++kst)
#pragma unroll
        for (int g = 0; g < 4; ++g)
            wreg[kst][g] = whh[(kst * 16 + g * 4 + w) * 64 + lane];

    float cst[16];
#pragma unroll
    for (int r = 0; r < 16; ++r) cst[r] = 0.0f;

    __syncthreads();   // drains stage(0) + wreg vmcnt; h zeros visible

#pragma unroll 2
    for (int t = 0; t < DEG; ++t) {
        const int buf = t & 1;

        // ---- acc init from staged Xu rows (gates i,f,g,o packed as u32x2)
        f32x16 acc[4];
#pragma unroll
        for (int r = 0; r < 16; ++r) {
            int m = (r & 3) + 8 * (r >> 2) + 4 * khalf;
            u32x2 v = ((const u32x2*)&stage[buf][m][0])[coff];
            acc[0][r] = __uint_as_float(v.x << 16);
            acc[1][r] = __uint_as_float(v.x & 0xFFFF0000u);
            acc[2][r] = __uint_as_float(v.y << 16);
            acc[3][r] = __uint_as_float(v.y & 0xFFFF0000u);
        }

        __syncthreads();   // barrier A: h(t-1) writes visible

        // ---- issue stage(t+1): async, drained at barrier B (full-step cover)
        if (t < DEG - 1) {
#pragma unroll
            for (int r8 = 0; r8 < 8; ++r8) {
                int m = w * 8 + r8;
                int idx = idxs[(t + 1) * 32 + m];
                const char* row = (const char*)xu + (size_t)idx * 1024;
                gld_lds16(row + lane * 16, &stage[buf ^ 1][m][0]);
            }
        }

        // ---- MFMA: A = h(t-1) from LDS, B = wreg
#pragma unroll
        for (int kst = 0; kst < 8; ++kst) {
            bf16x8 a = __builtin_bit_cast(bf16x8, h_frag[(kst * 2 + khalf) * 33 + mrow]);
#pragma unroll
            for (int g = 0; g < 4; ++g)
                acc[g] = __builtin_amdgcn_mfma_f32_32x32x16_bf16(
                    a, __builtin_bit_cast(bf16x8, wreg[kst][g]), acc[g], 0, 0, 0);
        }

        // ---- cell update (registers only)
        float hv16[16];
#pragma unroll
        for (int r = 0; r < 16; ++r) {
            float iv = fsigmoid(acc[0][r]);
            float fv = fsigmoid(acc[1][r]);
            float gv = ftanh(acc[2][r]);
            float ov = fsigmoid(acc[3][r]);
            float cv = __fmaf_rn(fv, cst[r], iv * gv);
            cst[r] = cv;
            hv16[r] = ov * ftanh(cv);
        }

        __syncthreads();   // barrier B: h(t-1) reads done; stage(t+1) drained

        // ---- h(t) write (A-frag layout, padded stride 33)
#pragma unroll
        for (int r = 0; r < 16; ++r) {
            uint32_t hb = __float_as_uint(hv16[r]) + 0x8000u;
            uint32_t pb = (uint32_t)__shfl_xor((int)hb, 1, 64);
            if ((lane & 1) == 0) {
                int row = (r & 3) + 8 * (r >> 2) + 4 * khalf;
                int j   = w * 32 + mrow;
                ((uint32_t*)h_frag)[((j >> 3) * 33 + row) * 4 + ((lane >> 1) & 3)] =
                    (hb >> 16) | (pb & 0xFFFF0000u);
            }
        }
    }

    __syncthreads();
    for (int i = tid; i < 32 * IN; i += 256) {
        int m = i >> 7, j = i & 127;
        int gn = node0 + m;
        if (gn < N)
            h_out[(size_t)gn * IN + j] =
                ((const ushort*)h_frag)[((j >> 3) * 33 + m) * 8 + (j & 7)];
    }
}

// ---------- output linear (fp32 math, bf16 inputs) ----------

template <int NOUT, int ACT, typename OutT>
__global__ __launch_bounds__(256) void k_out_linear(
    const ushort* __restrict__ x, const ushort* __restrict__ h,
    const float* __restrict__ wTs, const float* __restrict__ wTn,
    const float* __restrict__ bias, OutT* __restrict__ out, int N)
{
    constexpr int NPS = 32 / (256 / NOUT);
    __shared__ alignas(16) float x_lds[32][IN];
    __shared__ alignas(16) float h_lds[32][IN];

    const int tid  = threadIdx.x;
    const int j    = tid % NOUT;
    const int slot = tid / NOUT;
    const int node0 = blockIdx.x * 32;

    for (int i = tid; i < 32 * (IN / 8); i += 256) {
        int n = i >> 4, u4 = i & 15;
        int gn = node0 + n; if (gn >= N) gn = N - 1;
        u32x4 xv = *(const u32x4*)(x + (size_t)gn * IN + u4 * 8);
        u32x4 hv = *(const u32x4*)(h + (size_t)gn * IN + u4 * 8);
        float* xd = &x_lds[n][u4 * 8];
        float* hd = &h_lds[n][u4 * 8];
        xd[0] = __uint_as_float(xv.x << 16); xd[1] = __uint_as_float(xv.x & 0xFFFF0000u);
        xd[2] = __uint_as_float(xv.y << 16); xd[3] = __uint_as_float(xv.y & 0xFFFF0000u);
        xd[4] = __uint_as_float(xv.z << 16); xd[5] = __uint_as_float(xv.z & 0xFFFF0000u);
        xd[6] = __uint_as_float(xv.w << 16); xd[7] = __uint_as_float(xv.w & 0xFFFF0000u);
        hd[0] = __uint_as_float(hv.x << 16); hd[1] = __uint_as_float(hv.x & 0xFFFF0000u);
        hd[2] = __uint_as_float(hv.y << 16); hd[3] = __uint_as_float(hv.y & 0xFFFF0000u);
        hd[4] = __uint_as_float(hv.z << 16); hd[5] = __uint_as_float(hv.z & 0xFFFF0000u);
        hd[6] = __uint_as_float(hv.w << 16); hd[7] = __uint_as_float(hv.w & 0xFFFF0000u);
    }
    __syncthreads();

    float acc[NPS];
    const float bj = bias[j];
#pragma unroll
    for (int n = 0; n < NPS; ++n) acc[n] = bj;

#pragma unroll 2
    for (int k = 0; k < IN; ++k) {
        const float ws = wTs[k * NOUT + j];
        const float wn = wTn[k * NOUT + j];
#pragma unroll
        for (int n = 0; n < NPS; ++n) {
            acc[n] = __fmaf_rn(x_lds[slot * NPS + n][k], ws,
                     __fmaf_rn(h_lds[slot * NPS + n][k], wn, acc[n]));
        }
    }

#pragma unroll
    for (int n = 0; n < NPS; ++n) {
        int gn = node0 + slot * NPS + n;
        if (gn < N) {
            float v = acc[n];
            v = (ACT == 0) ? fmaxf(v, 0.0f) : fsigmoid(v);
            if constexpr (sizeof(OutT) == 2)
                out[(size_t)gn * NOUT + j] = (OutT)((__float_as_uint(v) + 0x8000u) >> 16);
            else
                out[(size_t)gn * NOUT + j] = v;
        }
    }
}

extern "C" void kernel_launch(void* const* d_in, const int* in_sizes, int n_in,
                              void* d_out, int out_size, void* d_ws, size_t ws_size,
                              hipStream_t stream)
{
    const float* feats    = (const float*)d_in[0];
    const int*   nbr      = (const int*)  d_in[1];
    const float* w_ih1    = (const float*)d_in[2];
    const float* w_hh1    = (const float*)d_in[3];
    const float* b_ih1    = (const float*)d_in[4];
    const float* b_hh1    = (const float*)d_in[5];
    const float* w_self1  = (const float*)d_in[6];
    const float* w_neigh1 = (const float*)d_in[7];
    const float* b1       = (const float*)d_in[8];
    const float* w_ih2    = (const float*)d_in[9];
    const float* w_hh2    = (const float*)d_in[10];
    const float* b_ih2    = (const float*)d_in[11];
    const float* b_hh2    = (const float*)d_in[12];
    const float* w_self2  = (const float*)d_in[13];
    const float* w_neigh2 = (const float*)d_in[14];
    const float* b2       = (const float*)d_in[15];
    float* out = (float*)d_out;

    const int N = in_sizes[0] / IN;   // 50000
    const long long Nceil = (N + 63) & ~63LL;

    char* ws = (char*)d_ws;
    size_t off = 0;
    auto alloc = [&](size_t bytes) -> void* {
        void* p = (void*)(ws + off);
        off += (bytes + 255) & ~(size_t)255;
        return p;
    };
    u32x4*  wfrag_ih1 = (u32x4*)alloc(8192 * 16);
    u32x4*  wfrag_hh1 = (u32x4*)alloc(8192 * 16);
    u32x4*  wfrag_ih2 = (u32x4*)alloc(8192 * 16);
    u32x4*  wfrag_hh2 = (u32x4*)alloc(8192 * 16);
    float*  wT_self1  = (float*)alloc(128 * 128 * 4);
    float*  wT_neigh1 = (float*)alloc(128 * 128 * 4);
    float*  wT_self2  = (float*)alloc(64 * 128 * 4);
    float*  wT_neigh2 = (float*)alloc(64 * 128 * 4);
    float*  bsum1     = (float*)alloc(512 * 4);
    float*  bsum2     = (float*)alloc(512 * 4);
    ushort* feats_bf  = (ushort*)alloc((size_t)N * 128 * 2);
    ushort* h_buf     = (ushort*)alloc((size_t)N * 128 * 2);
    ushort* out1      = (ushort*)alloc((size_t)N * 128 * 2);
    u32x2*  xu_buf    = (u32x2*)alloc((size_t)Nceil * 128 * 8);   // 51.25MB

    // prep
    k_pack_w8<<<dim3(32), dim3(256), 0, stream>>>(w_ih1, wfrag_ih1);
    k_pack_w8<<<dim3(32), dim3(256), 0, stream>>>(w_hh1, wfrag_hh1);
    k_pack_w8<<<dim3(32), dim3(256), 0, stream>>>(w_ih2, wfrag_ih2);
    k_pack_w8<<<dim3(32), dim3(256), 0, stream>>>(w_hh2, wfrag_hh2);
    k_transpose<<<dim3((128 * 128 + 255) / 256), dim3(256), 0, stream>>>(w_self1, wT_self1, 128, 128);
    k_transpose<<<dim3((128 * 128 + 255) / 256), dim3(256), 0, stream>>>(w_neigh1, wT_neigh1, 128, 128);
    k_transpose<<<dim3((64 * 128 + 255) / 256), dim3(256), 0, stream>>>(w_self2, wT_self2, 64, 128);
    k_transpose<<<dim3((64 * 128 + 255) / 256), dim3(256), 0, stream>>>(w_neigh2, wT_neigh2, 64, 128);
    k_bias_sum<<<dim3(2), dim3(256), 0, stream>>>(b_ih1, b_hh1, bsum1, 512);
    k_bias_sum<<<dim3(2), dim3(256), 0, stream>>>(b_ih2, b_hh2, bsum2, 512);
    k_cast_bf16<<<dim3((N * 128 / 4 + 255) / 256), dim3(256), 0, stream>>>(feats, feats_bf, N * 128);

    const int nblk64 = (int)(Nceil / 64);
    const int nblk32 = (N + 31) / 32;

    // layer 1
    k_xu<<<dim3(nblk64), dim3(256), 0, stream>>>(feats_bf, wfrag_ih1, bsum1, xu_buf, N);
    k_lstm_rec3<<<dim3(nblk32), dim3(256), 0, stream>>>(xu_buf, nbr, wfrag_hh1, h_buf, N);
    k_out_linear<128, 0, ushort><<<dim3(nblk32), dim3(256), 0, stream>>>(feats_bf, h_buf, wT_self1, wT_neigh1, b1, out1, N);

    // layer 2
    k_xu<<<dim3(nblk64), dim3(256), 0, stream>>>(out1, wfrag_ih2, bsum2, xu_buf, N);
    k_lstm_rec3<<<dim3(nblk32), dim3(256), 0, stream>>>(xu_buf, nbr, wfrag_hh2, h_buf, N);
    k_out_linear<64, 1, float><<<dim3(nblk32), dim3(256), 0, stream>>>(out1, h_buf, wT_self2, wT_neigh2, b2, out, N);
}